// Round 6
// baseline (709.787 us; speedup 1.0000x reference)
//
#include <hip/hip_runtime.h>
#include <math.h>

#define EPS 1e-6f
#define NE 64
#define TPB 1024
#define WPB 16             // waves per block
#define NBLK 256           // 1 block/CU (persistent residency requires this)
#define NWAVES (NBLK * WPB)   // 4096
#define ITERS 10
#define QPW 32             // quads per wave (131072 / 4096)
#define NR 16              // register-resident quads (exp-precomputed, 64 VGPR)
#define NL 8               // LDS-resident quads (exp-precomputed, 128 KB dyn)

// ---- DPP helpers: 16-lane-group reductions, pure VALU (no ds ops) ----
template <int ctrl>
__device__ __forceinline__ float dppf(float x) {
    return __int_as_float(__builtin_amdgcn_update_dpp(
        0, __float_as_int(x), ctrl, 0xf, 0xf, true));
}
template <int ctrl>
__device__ __forceinline__ int dppi(int x) {
    return __builtin_amdgcn_update_dpp(0, x, ctrl, 0xf, 0xf, true);
}

__device__ __forceinline__ float group16_sum(float v) {
    v += dppf<0xB1>(v);   // quad_perm xor 1
    v += dppf<0x4E>(v);   // quad_perm xor 2
    v += dppf<0x141>(v);  // row_half_mirror (xor 4)
    v += dppf<0x140>(v);  // row_mirror (xor 8)
    return v;
}

#define ARGMAX_STEP(CTRL)                                      \
    {                                                          \
        float ov = dppf<CTRL>(v);                              \
        int oi = dppi<CTRL>(i);                                \
        if (ov > v || (ov == v && oi < i)) { v = ov; i = oi; } \
    }

__device__ __forceinline__ void group16_argmax(float& v, int& i) {
    ARGMAX_STEP(0xB1)
    ARGMAX_STEP(0x4E)
    ARGMAX_STEP(0x141)
    ARGMAX_STEP(0x140)
}

// Persistent fused kernel, round 6: on-chip residency, spill fixed.
// R5 post-mortem: missing __launch_bounds__ min-waves let the compiler cap
// VGPRs at 64 -> RD[16] spilled to scratch (WRITE_SIZE 9->116 MB). Fix:
// launch_bounds(1024,4) (VGPR cap 128) + peak-pressure trim (single rotating
// stream buffer; no cur[] copy in pass 0). Live set <= ~110 regs.
// Residency plan per wave (32 quads):
//   q 0..15  -> VGPRs (RD, exp computed once in pass 0)
//   q 16..23 -> LDS   (128 KB dynamic/block, exp computed once)
//   q 24..31 -> streamed each pass (4 MB/XCD aggregate = L2-resident)
// Arithmetic order (q0->q31, same __expf/div forms) identical to validated
// R2 kernel -> bitwise-identical output. Barrier machinery unchanged.
__global__ __launch_bounds__(TPB, 4) void sink_fused(
    const float4* __restrict__ logits4,
    float* __restrict__ Pblk,          // [2][NBLK][NE]
    unsigned* __restrict__ counters,   // [ITERS]
    float2* __restrict__ oidx, float2* __restrict__ ow,
    int nquads, float col_target) {
    extern __shared__ float4 ldsq[];   // [WPB*NL*64] = 128 KB resident data
    __shared__ float4 plds[WPB][64];   // 16 KB  block column-partial buffer
    __shared__ float s_red[16][NE];    // 4 KB   chunk-reduce buffer
    __shared__ float r_lds[WPB * 128]; // 8 KB   per-row r (2048 rows/block)
    __shared__ float4 c_lds4[NE / 4];  // 256 B  current column scaling

    const int tid = threadIdx.x;
    const int lane = tid & 63;
    const int wib = tid >> 6;
    const int g = lane >> 4;   // row within quad
    const int h = lane & 15;   // float4 slot within row
    const int qbase = (blockIdx.x * WPB + wib) * QPW;
    const float4* lp = logits4 + (size_t)qbase * 64 + lane;
    const int lrow0 = wib * 128 + g;

    if (tid < NE / 4) c_lds4[tid] = make_float4(1.f, 1.f, 1.f, 1.f);
    __syncthreads();

    auto exp4 = [](const float4& v) {
        float4 e;
        e.x = __expf(v.x); e.y = __expf(v.y);
        e.z = __expf(v.z); e.w = __expf(v.w);
        return e;
    };

    // per-quad Sinkhorn row step (same expression forms as validated R2)
    auto procq = [&](const float4& e, int q, const float4& c4, float4& pacc,
                     bool first) {
        float s = e.x * c4.x + e.y * c4.y + e.z * c4.z + e.w * c4.w;
        s = group16_sum(s);
        const int lrow = lrow0 + q * 4;
        float rold = first ? 1.0f : r_lds[lrow];
        float rnew = rold / (rold * s + EPS);
        if (h == 0) r_lds[lrow] = rnew;
        pacc.x += e.x * rnew; pacc.y += e.y * rnew;
        pacc.z += e.z * rnew; pacc.w += e.w * rnew;
    };

    // block column-reduce + grid barrier + global reduce + c update
    // (identical structure/order to validated R2 kernel)
    auto col_reduce_barrier = [&](const float4& pacc, int it) {
        float* Pcur = Pblk + (size_t)(it & 1) * NBLK * NE;
        plds[wib][lane] = pacc;
        __syncthreads();
        if (tid < NE) {
            const int hh = tid >> 2, kk = tid & 3;
            float t = 0.f;
#pragma unroll
            for (int w = 0; w < WPB; ++w)
#pragma unroll
                for (int gg = 0; gg < 4; ++gg)
                    t += ((const float*)&plds[w][gg * 16 + hh])[kk];
            __hip_atomic_store(&Pcur[blockIdx.x * NE + tid], t,
                               __ATOMIC_RELAXED, __HIP_MEMORY_SCOPE_AGENT);
        }
        __syncthreads();   // partials drained before arrival
        if (tid == 0) {
            __builtin_amdgcn_fence(__ATOMIC_RELEASE, "agent");
            __hip_atomic_fetch_add(&counters[it], 1u, __ATOMIC_RELAXED,
                                   __HIP_MEMORY_SCOPE_AGENT);
            while (__hip_atomic_load(&counters[it], __ATOMIC_RELAXED,
                                     __HIP_MEMORY_SCOPE_AGENT) < (unsigned)NBLK)
                __builtin_amdgcn_s_sleep(2);
            __builtin_amdgcn_fence(__ATOMIC_ACQUIRE, "agent");
        }
        __syncthreads();
        {
            const int col = tid & 63;
            const int chunk = tid >> 6;          // 16 chunks of 16 blocks
            const int b0 = chunk * (NBLK / 16);
            float t = 0.f;
#pragma unroll
            for (int b2 = 0; b2 < NBLK / 16; ++b2)
                t += __hip_atomic_load(&Pcur[(b0 + b2) * NE + col],
                                       __ATOMIC_RELAXED,
                                       __HIP_MEMORY_SCOPE_AGENT);
            s_red[chunk][col] = t;
        }
        __syncthreads();
        if (tid < NE) {
            float P = 0.f;
#pragma unroll
            for (int k = 0; k < 16; ++k) P += s_red[k][tid];
            float cj = ((float*)c_lds4)[tid];
            ((float*)c_lds4)[tid] = cj * col_target / (cj * P + EPS);
        }
        __syncthreads();
    };

    float4 RD[NR];   // register-resident exp(logits), compile-time indexed

    // ---- pass 0: stream everything, stash exp into RD/LDS -----------------
    // Rotating buf[4]: process buf[p], immediately reload it with the next
    // batch's quad -> only one 4-quad buffer live (peak-VGPR control).
    {
        const float4 c4 = c_lds4[h];   // all ones
        float4 buf[4];
#pragma unroll
        for (int p = 0; p < 4; ++p) buf[p] = lp[(size_t)p * 64];
        float4 pacc = {0.f, 0.f, 0.f, 0.f};
#pragma unroll
        for (int b = 0; b < 8; ++b) {
#pragma unroll
            for (int p = 0; p < 4; ++p) {
                const int q = b * 4 + p;           // compile-time constant
                float4 x = buf[p];
                if (b < 7) buf[p] = lp[(size_t)((b + 1) * 4 + p) * 64];
                float4 e = exp4(x);
                if (q < NR) RD[q] = e;
                else if (q < NR + NL)
                    ldsq[(wib * NL + (q - NR)) * 64 + lane] = e;
                procq(e, q, c4, pacc, true);
            }
        }
        col_reduce_barrier(pacc, 0);
    }

    // ---- passes 1..9: residents + small L2-resident streamed tail ---------
    for (int it = 1; it < ITERS; ++it) {
        const float4 c4 = c_lds4[h];
        float4 sbuf[4];
#pragma unroll
        for (int p = 0; p < 4; ++p) sbuf[p] = lp[(size_t)(24 + p) * 64];

        float4 pacc = {0.f, 0.f, 0.f, 0.f};
#pragma unroll
        for (int q = 0; q < NR; ++q) procq(RD[q], q, c4, pacc, false);

        // LDS residents, 1-deep pipelined reads
        float4 lcur = ldsq[(wib * NL) * 64 + lane];
#pragma unroll
        for (int j = 0; j < NL; ++j) {
            float4 lnxt;
            if (j + 1 < NL) lnxt = ldsq[(wib * NL + j + 1) * 64 + lane];
            procq(lcur, NR + j, c4, pacc, false);
            lcur = lnxt;
        }

        // q24-27: rotate sbuf in place -> q28-31 loads issued before use
#pragma unroll
        for (int p = 0; p < 4; ++p) {
            float4 x = sbuf[p];
            sbuf[p] = lp[(size_t)(28 + p) * 64];
            procq(exp4(x), 24 + p, c4, pacc, false);
        }
#pragma unroll
        for (int p = 0; p < 4; ++p)
            procq(exp4(sbuf[p]), 28 + p, c4, pacc, false);

        col_reduce_barrier(pacc, it);
    }

    // ---- final: row-normalize + top-2 (DPP argmax) + renorm ---------------
    {
        const float4 c4 = c_lds4[h];
        const int base_col = h * 4;

        auto top2 = [&](const float4& e, int q) {
            float4 u;
            u.x = e.x * c4.x; u.y = e.y * c4.y;
            u.z = e.z * c4.z; u.w = e.w * c4.w;
            float s = group16_sum(u.x + u.y + u.z + u.w);
            const int lrow = lrow0 + q * 4;
            float rold = r_lds[lrow];
            float rnew = rold / (rold * s + EPS);
            float4 val;
            val.x = u.x * rnew; val.y = u.y * rnew;
            val.z = u.z * rnew; val.w = u.w * rnew;

            float v = val.x; int i = base_col;
            if (val.y > v) { v = val.y; i = base_col + 1; }
            if (val.z > v) { v = val.z; i = base_col + 2; }
            if (val.w > v) { v = val.w; i = base_col + 3; }
            group16_argmax(v, i);
            float v1 = v; int i1 = i;

            float4 mv;
            mv.x = (i1 == base_col)     ? -INFINITY : val.x;
            mv.y = (i1 == base_col + 1) ? -INFINITY : val.y;
            mv.z = (i1 == base_col + 2) ? -INFINITY : val.z;
            mv.w = (i1 == base_col + 3) ? -INFINITY : val.w;
            v = mv.x; i = base_col;
            if (mv.y > v) { v = mv.y; i = base_col + 1; }
            if (mv.z > v) { v = mv.z; i = base_col + 2; }
            if (mv.w > v) { v = mv.w; i = base_col + 3; }
            group16_argmax(v, i);
            float v2 = v; int i2 = i;

            if (h == 0) {
                int row = (qbase + q) * 4 + g;
                float wsum = v1 + v2 + EPS;
                oidx[row] = make_float2((float)i1, (float)i2);
                ow[row] = make_float2(v1 / wsum, v2 / wsum);
            }
        };

        float4 sbuf[4];
#pragma unroll
        for (int p = 0; p < 4; ++p) sbuf[p] = lp[(size_t)(24 + p) * 64];

#pragma unroll
        for (int q = 0; q < NR; ++q) top2(RD[q], q);

        float4 lcur = ldsq[(wib * NL) * 64 + lane];
#pragma unroll
        for (int j = 0; j < NL; ++j) {
            float4 lnxt;
            if (j + 1 < NL) lnxt = ldsq[(wib * NL + j + 1) * 64 + lane];
            top2(lcur, NR + j);
            lcur = lnxt;
        }

#pragma unroll
        for (int p = 0; p < 4; ++p) {
            float4 x = sbuf[p];
            sbuf[p] = lp[(size_t)(28 + p) * 64];
            top2(exp4(x), 24 + p);
        }
#pragma unroll
        for (int p = 0; p < 4; ++p) top2(exp4(sbuf[p]), 28 + p);
    }
}

extern "C" void kernel_launch(void* const* d_in, const int* in_sizes, int n_in,
                              void* d_out, int out_size, void* d_ws, size_t ws_size,
                              hipStream_t stream) {
    const float* logits = (const float*)d_in[0];
    const int S = in_sizes[0] / NE;            // 524288
    const int nquads = S / 4;                  // 131072 (divisible by NWAVES)
    const float col_target = (float)S / (float)NE;

    float* Pblk = (float*)d_ws;                // 2*NBLK*64 floats (dbuf)
    unsigned* counters = (unsigned*)(Pblk + 2 * NBLK * NE);  // ITERS slots

    float* out = (float*)d_out;
    float2* oidx = (float2*)out;               // 2*S floats (indices)
    float2* ow = (float2*)(out + (size_t)2 * S);  // 2*S floats (weights)

    const size_t dyn_lds = (size_t)WPB * NL * 64 * sizeof(float4);  // 128 KB
    static bool attr_done = false;
    if (!attr_done) {
        hipFuncSetAttribute(reinterpret_cast<const void*>(sink_fused),
                            hipFuncAttributeMaxDynamicSharedMemorySize,
                            (int)dyn_lds);
        attr_done = true;
    }

    hipMemsetAsync(counters, 0, ITERS * sizeof(unsigned), stream);
    sink_fused<<<NBLK, TPB, dyn_lds, stream>>>((const float4*)logits, Pblk,
                                               counters, oidx, ow, nquads,
                                               col_target);
}

// Round 7
// 697.546 us; speedup vs baseline: 1.0175x; 1.0175x over previous
//
#include <hip/hip_runtime.h>
#include <math.h>

#define EPS 1e-6f
#define NE 64
#define TPB 1024
#define WPB 16             // waves per block
#define NBLK 256           // 1 block/CU (persistent residency requires this)
#define NWAVES (NBLK * WPB)   // 4096
#define ITERS 10
#define QPW 32             // quads per wave (131072 / 4096)
#define NR 16              // register-resident quads (exp-precomputed, 64 VGPR)
#define NL 8               // LDS-resident quads (exp-precomputed, 128 KB dyn)

// ---- DPP helpers: 16-lane-group reductions, pure VALU (no ds ops) ----
template <int ctrl>
__device__ __forceinline__ float dppf(float x) {
    return __int_as_float(__builtin_amdgcn_update_dpp(
        0, __float_as_int(x), ctrl, 0xf, 0xf, true));
}
template <int ctrl>
__device__ __forceinline__ int dppi(int x) {
    return __builtin_amdgcn_update_dpp(0, x, ctrl, 0xf, 0xf, true);
}

__device__ __forceinline__ float group16_sum(float v) {
    v += dppf<0xB1>(v);   // quad_perm xor 1
    v += dppf<0x4E>(v);   // quad_perm xor 2
    v += dppf<0x141>(v);  // row_half_mirror (xor 4)
    v += dppf<0x140>(v);  // row_mirror (xor 8)
    return v;
}

#define ARGMAX_STEP(CTRL)                                      \
    {                                                          \
        float ov = dppf<CTRL>(v);                              \
        int oi = dppi<CTRL>(i);                                \
        if (ov > v || (ov == v && oi < i)) { v = ov; i = oi; } \
    }

__device__ __forceinline__ void group16_argmax(float& v, int& i) {
    ARGMAX_STEP(0xB1)
    ARGMAX_STEP(0x4E)
    ARGMAX_STEP(0x141)
    ARGMAX_STEP(0x140)
}

// Persistent fused kernel, round 7: on-chip residency, spill ACTUALLY fixed.
// R6 post-mortem: VGPR_Count=64 + WRITE_SIZE=114MB persisted. The compiler
// targets 8 waves/EU (64-reg allocation point) because the 128KB resident
// buffer is DYNAMIC shared memory -- invisible at compile time, so it can't
// see occupancy is already LDS-capped at 4 waves/EU. launch_bounds' min-waves
// hint didn't stop the allocator from spilling RD to chase phantom occupancy.
// Fix: amdgpu_waves_per_eu(4,4) pins min=max=4 -> VGPR budget 512/4=128,
// no incentive to shrink -> RD[16] stays in registers. Runtime occupancy
// unchanged (LDS already forces 1 block/CU = 4 waves/EU).
// Residency plan per wave (32 quads):
//   q 0..15  -> VGPRs (RD, exp computed once in pass 0)
//   q 16..23 -> LDS   (128 KB dynamic/block, exp computed once)
//   q 24..31 -> streamed each pass (4 MB/XCD aggregate = L2-resident)
// Arithmetic order (q0->q31, same __expf/div forms) identical to validated
// R2 kernel -> bitwise-identical output. Barrier machinery unchanged.
__global__ __attribute__((amdgpu_flat_work_group_size(TPB, TPB),
                          amdgpu_waves_per_eu(4, 4))) void sink_fused(
    const float4* __restrict__ logits4,
    float* __restrict__ Pblk,          // [2][NBLK][NE]
    unsigned* __restrict__ counters,   // [ITERS]
    float2* __restrict__ oidx, float2* __restrict__ ow,
    int nquads, float col_target) {
    extern __shared__ float4 ldsq[];   // [WPB*NL*64] = 128 KB resident data
    __shared__ float4 plds[WPB][64];   // 16 KB  block column-partial buffer
    __shared__ float s_red[16][NE];    // 4 KB   chunk-reduce buffer
    __shared__ float r_lds[WPB * 128]; // 8 KB   per-row r (2048 rows/block)
    __shared__ float4 c_lds4[NE / 4];  // 256 B  current column scaling

    const int tid = threadIdx.x;
    const int lane = tid & 63;
    const int wib = tid >> 6;
    const int g = lane >> 4;   // row within quad
    const int h = lane & 15;   // float4 slot within row
    const int qbase = (blockIdx.x * WPB + wib) * QPW;
    const float4* lp = logits4 + (size_t)qbase * 64 + lane;
    const int lrow0 = wib * 128 + g;

    if (tid < NE / 4) c_lds4[tid] = make_float4(1.f, 1.f, 1.f, 1.f);
    __syncthreads();

    auto exp4 = [](const float4& v) {
        float4 e;
        e.x = __expf(v.x); e.y = __expf(v.y);
        e.z = __expf(v.z); e.w = __expf(v.w);
        return e;
    };

    // per-quad Sinkhorn row step (same expression forms as validated R2)
    auto procq = [&](const float4& e, int q, const float4& c4, float4& pacc,
                     bool first) {
        float s = e.x * c4.x + e.y * c4.y + e.z * c4.z + e.w * c4.w;
        s = group16_sum(s);
        const int lrow = lrow0 + q * 4;
        float rold = first ? 1.0f : r_lds[lrow];
        float rnew = rold / (rold * s + EPS);
        if (h == 0) r_lds[lrow] = rnew;
        pacc.x += e.x * rnew; pacc.y += e.y * rnew;
        pacc.z += e.z * rnew; pacc.w += e.w * rnew;
    };

    // block column-reduce + grid barrier + global reduce + c update
    // (identical structure/order to validated R2 kernel)
    auto col_reduce_barrier = [&](const float4& pacc, int it) {
        float* Pcur = Pblk + (size_t)(it & 1) * NBLK * NE;
        plds[wib][lane] = pacc;
        __syncthreads();
        if (tid < NE) {
            const int hh = tid >> 2, kk = tid & 3;
            float t = 0.f;
#pragma unroll
            for (int w = 0; w < WPB; ++w)
#pragma unroll
                for (int gg = 0; gg < 4; ++gg)
                    t += ((const float*)&plds[w][gg * 16 + hh])[kk];
            __hip_atomic_store(&Pcur[blockIdx.x * NE + tid], t,
                               __ATOMIC_RELAXED, __HIP_MEMORY_SCOPE_AGENT);
        }
        __syncthreads();   // partials drained before arrival
        if (tid == 0) {
            __builtin_amdgcn_fence(__ATOMIC_RELEASE, "agent");
            __hip_atomic_fetch_add(&counters[it], 1u, __ATOMIC_RELAXED,
                                   __HIP_MEMORY_SCOPE_AGENT);
            while (__hip_atomic_load(&counters[it], __ATOMIC_RELAXED,
                                     __HIP_MEMORY_SCOPE_AGENT) < (unsigned)NBLK)
                __builtin_amdgcn_s_sleep(2);
            __builtin_amdgcn_fence(__ATOMIC_ACQUIRE, "agent");
        }
        __syncthreads();
        {
            const int col = tid & 63;
            const int chunk = tid >> 6;          // 16 chunks of 16 blocks
            const int b0 = chunk * (NBLK / 16);
            float t = 0.f;
#pragma unroll
            for (int b2 = 0; b2 < NBLK / 16; ++b2)
                t += __hip_atomic_load(&Pcur[(b0 + b2) * NE + col],
                                       __ATOMIC_RELAXED,
                                       __HIP_MEMORY_SCOPE_AGENT);
            s_red[chunk][col] = t;
        }
        __syncthreads();
        if (tid < NE) {
            float P = 0.f;
#pragma unroll
            for (int k = 0; k < 16; ++k) P += s_red[k][tid];
            float cj = ((float*)c_lds4)[tid];
            ((float*)c_lds4)[tid] = cj * col_target / (cj * P + EPS);
        }
        __syncthreads();
    };

    float4 RD[NR];   // register-resident exp(logits), compile-time indexed

    // ---- pass 0: stream everything, stash exp into RD/LDS -----------------
    // Rotating buf[4]: process buf[p], immediately reload it with the next
    // batch's quad -> only one 4-quad buffer live (peak-VGPR control).
    {
        const float4 c4 = c_lds4[h];   // all ones
        float4 buf[4];
#pragma unroll
        for (int p = 0; p < 4; ++p) buf[p] = lp[(size_t)p * 64];
        float4 pacc = {0.f, 0.f, 0.f, 0.f};
#pragma unroll
        for (int b = 0; b < 8; ++b) {
#pragma unroll
            for (int p = 0; p < 4; ++p) {
                const int q = b * 4 + p;           // compile-time constant
                float4 x = buf[p];
                if (b < 7) buf[p] = lp[(size_t)((b + 1) * 4 + p) * 64];
                float4 e = exp4(x);
                if (q < NR) RD[q] = e;
                else if (q < NR + NL)
                    ldsq[(wib * NL + (q - NR)) * 64 + lane] = e;
                procq(e, q, c4, pacc, true);
            }
        }
        col_reduce_barrier(pacc, 0);
    }

    // ---- passes 1..9: residents + small L2-resident streamed tail ---------
    for (int it = 1; it < ITERS; ++it) {
        const float4 c4 = c_lds4[h];
        float4 sbuf[4];
#pragma unroll
        for (int p = 0; p < 4; ++p) sbuf[p] = lp[(size_t)(24 + p) * 64];

        float4 pacc = {0.f, 0.f, 0.f, 0.f};
#pragma unroll
        for (int q = 0; q < NR; ++q) procq(RD[q], q, c4, pacc, false);

        // LDS residents, 1-deep pipelined reads
        float4 lcur = ldsq[(wib * NL) * 64 + lane];
#pragma unroll
        for (int j = 0; j < NL; ++j) {
            float4 lnxt;
            if (j + 1 < NL) lnxt = ldsq[(wib * NL + j + 1) * 64 + lane];
            procq(lcur, NR + j, c4, pacc, false);
            lcur = lnxt;
        }

        // q24-27: rotate sbuf in place -> q28-31 loads issued before use
#pragma unroll
        for (int p = 0; p < 4; ++p) {
            float4 x = sbuf[p];
            sbuf[p] = lp[(size_t)(28 + p) * 64];
            procq(exp4(x), 24 + p, c4, pacc, false);
        }
#pragma unroll
        for (int p = 0; p < 4; ++p)
            procq(exp4(sbuf[p]), 28 + p, c4, pacc, false);

        col_reduce_barrier(pacc, it);
    }

    // ---- final: row-normalize + top-2 (DPP argmax) + renorm ---------------
    {
        const float4 c4 = c_lds4[h];
        const int base_col = h * 4;

        auto top2 = [&](const float4& e, int q) {
            float4 u;
            u.x = e.x * c4.x; u.y = e.y * c4.y;
            u.z = e.z * c4.z; u.w = e.w * c4.w;
            float s = group16_sum(u.x + u.y + u.z + u.w);
            const int lrow = lrow0 + q * 4;
            float rold = r_lds[lrow];
            float rnew = rold / (rold * s + EPS);
            float4 val;
            val.x = u.x * rnew; val.y = u.y * rnew;
            val.z = u.z * rnew; val.w = u.w * rnew;

            float v = val.x; int i = base_col;
            if (val.y > v) { v = val.y; i = base_col + 1; }
            if (val.z > v) { v = val.z; i = base_col + 2; }
            if (val.w > v) { v = val.w; i = base_col + 3; }
            group16_argmax(v, i);
            float v1 = v; int i1 = i;

            float4 mv;
            mv.x = (i1 == base_col)     ? -INFINITY : val.x;
            mv.y = (i1 == base_col + 1) ? -INFINITY : val.y;
            mv.z = (i1 == base_col + 2) ? -INFINITY : val.z;
            mv.w = (i1 == base_col + 3) ? -INFINITY : val.w;
            v = mv.x; i = base_col;
            if (mv.y > v) { v = mv.y; i = base_col + 1; }
            if (mv.z > v) { v = mv.z; i = base_col + 2; }
            if (mv.w > v) { v = mv.w; i = base_col + 3; }
            group16_argmax(v, i);
            float v2 = v; int i2 = i;

            if (h == 0) {
                int row = (qbase + q) * 4 + g;
                float wsum = v1 + v2 + EPS;
                oidx[row] = make_float2((float)i1, (float)i2);
                ow[row] = make_float2(v1 / wsum, v2 / wsum);
            }
        };

        float4 sbuf[4];
#pragma unroll
        for (int p = 0; p < 4; ++p) sbuf[p] = lp[(size_t)(24 + p) * 64];

#pragma unroll
        for (int q = 0; q < NR; ++q) top2(RD[q], q);

        float4 lcur = ldsq[(wib * NL) * 64 + lane];
#pragma unroll
        for (int j = 0; j < NL; ++j) {
            float4 lnxt;
            if (j + 1 < NL) lnxt = ldsq[(wib * NL + j + 1) * 64 + lane];
            top2(lcur, NR + j);
            lcur = lnxt;
        }

#pragma unroll
        for (int p = 0; p < 4; ++p) {
            float4 x = sbuf[p];
            sbuf[p] = lp[(size_t)(28 + p) * 64];
            top2(exp4(x), 24 + p);
        }
#pragma unroll
        for (int p = 0; p < 4; ++p) top2(exp4(sbuf[p]), 28 + p);
    }
}

extern "C" void kernel_launch(void* const* d_in, const int* in_sizes, int n_in,
                              void* d_out, int out_size, void* d_ws, size_t ws_size,
                              hipStream_t stream) {
    const float* logits = (const float*)d_in[0];
    const int S = in_sizes[0] / NE;            // 524288
    const int nquads = S / 4;                  // 131072 (divisible by NWAVES)
    const float col_target = (float)S / (float)NE;

    float* Pblk = (float*)d_ws;                // 2*NBLK*64 floats (dbuf)
    unsigned* counters = (unsigned*)(Pblk + 2 * NBLK * NE);  // ITERS slots

    float* out = (float*)d_out;
    float2* oidx = (float2*)out;               // 2*S floats (indices)
    float2* ow = (float2*)(out + (size_t)2 * S);  // 2*S floats (weights)

    const size_t dyn_lds = (size_t)WPB * NL * 64 * sizeof(float4);  // 128 KB
    static bool attr_done = false;
    if (!attr_done) {
        hipFuncSetAttribute(reinterpret_cast<const void*>(sink_fused),
                            hipFuncAttributeMaxDynamicSharedMemorySize,
                            (int)dyn_lds);
        attr_done = true;
    }

    hipMemsetAsync(counters, 0, ITERS * sizeof(unsigned), stream);
    sink_fused<<<NBLK, TPB, dyn_lds, stream>>>((const float4*)logits, Pblk,
                                               counters, oidx, ow, nquads,
                                               col_target);
}

// Round 8
// 666.931 us; speedup vs baseline: 1.0643x; 1.0459x over previous
//
#include <hip/hip_runtime.h>
#include <math.h>

#define EPS 1e-6f
#define NE 64
#define TPB 1024
#define WPB 16             // waves per block
#define NBLK 256           // 1 block/CU (persistent residency requires this)
#define NWAVES (NBLK * WPB)   // 4096
#define ITERS 10
#define QPW 32             // quads per wave (131072 / 4096)
#define NR 16              // register-resident quads (named vars, no array!)
#define NL 8               // LDS-resident quads (128 KB dynamic)

// ---- DPP helpers: 16-lane-group reductions, pure VALU (no ds ops) ----
template <int ctrl>
__device__ __forceinline__ float dppf(float x) {
    return __int_as_float(__builtin_amdgcn_update_dpp(
        0, __float_as_int(x), ctrl, 0xf, 0xf, true));
}
template <int ctrl>
__device__ __forceinline__ int dppi(int x) {
    return __builtin_amdgcn_update_dpp(0, x, ctrl, 0xf, 0xf, true);
}

__device__ __forceinline__ float group16_sum(float v) {
    v += dppf<0xB1>(v);   // quad_perm xor 1
    v += dppf<0x4E>(v);   // quad_perm xor 2
    v += dppf<0x141>(v);  // row_half_mirror (xor 4)
    v += dppf<0x140>(v);  // row_mirror (xor 8)
    return v;
}

#define ARGMAX_STEP(CTRL)                                      \
    {                                                          \
        float ov = dppf<CTRL>(v);                              \
        int oi = dppi<CTRL>(i);                                \
        if (ov > v || (ov == v && oi < i)) { v = ov; i = oi; } \
    }

__device__ __forceinline__ void group16_argmax(float& v, int& i) {
    ARGMAX_STEP(0xB1)
    ARGMAX_STEP(0x4E)
    ARGMAX_STEP(0x141)
    ARGMAX_STEP(0x140)
}

// Persistent fused kernel, round 8: residency WITHOUT an array.
// R5-R7 post-mortem: WRITE_SIZE pinned at exactly 114MB and VGPR at exactly
// 64 across three different occupancy attributes => not a pressure spill;
// the RD[16] ALLOCA was never promoted (rule #20: address escaped via
// const-ref lambda param + complex loop nest defeated SROA). Scratch from
// the front end; attributes can't help.
// Fix: 16 NAMED float4 registers (R0..R15), macro-generated literal-index
// access, helpers take operands BY VALUE. No alloca can exist.
// Residency plan per wave (32 quads):
//   q 0..15  -> named VGPR vars (exp computed once in pass 0)
//   q 16..23 -> LDS (128 KB dynamic/block, exp computed once)
//   q 24..31 -> streamed each pass (4 MB/XCD aggregate = L2-resident)
// Arithmetic order (q0->q31, same __expf/div forms) identical to validated
// R2 kernel -> bitwise-identical output. Barrier machinery unchanged.
__global__ __launch_bounds__(TPB, 4) void sink_fused(
    const float4* __restrict__ logits4,
    float* __restrict__ Pblk,          // [2][NBLK][NE]
    unsigned* __restrict__ counters,   // [ITERS]
    float2* __restrict__ oidx, float2* __restrict__ ow,
    int nquads, float col_target) {
    extern __shared__ float4 ldsq[];   // [WPB*NL*64] = 128 KB resident data
    __shared__ float4 plds[WPB][64];   // 16 KB  block column-partial buffer
    __shared__ float s_red[16][NE];    // 4 KB   chunk-reduce buffer
    __shared__ float r_lds[WPB * 128]; // 8 KB   per-row r (2048 rows/block)
    __shared__ float4 c_lds4[NE / 4];  // 256 B  current column scaling

    const int tid = threadIdx.x;
    const int lane = tid & 63;
    const int wib = tid >> 6;
    const int g = lane >> 4;   // row within quad
    const int h = lane & 15;   // float4 slot within row
    const int qbase = (blockIdx.x * WPB + wib) * QPW;
    const float4* lp = logits4 + (size_t)qbase * 64 + lane;
    const int lrow0 = wib * 128 + g;

    if (tid < NE / 4) c_lds4[tid] = make_float4(1.f, 1.f, 1.f, 1.f);
    __syncthreads();

    auto exp4 = [](float4 v) {
        float4 e;
        e.x = __expf(v.x); e.y = __expf(v.y);
        e.z = __expf(v.z); e.w = __expf(v.w);
        return e;
    };

    // per-quad Sinkhorn row step -- operand BY VALUE (no address escape)
    auto procq = [&](float4 e, int q, float4 c4, float4& pacc, bool first) {
        float s = e.x * c4.x + e.y * c4.y + e.z * c4.z + e.w * c4.w;
        s = group16_sum(s);
        const int lrow = lrow0 + q * 4;
        float rold = first ? 1.0f : r_lds[lrow];
        float rnew = rold / (rold * s + EPS);
        if (h == 0) r_lds[lrow] = rnew;
        pacc.x += e.x * rnew; pacc.y += e.y * rnew;
        pacc.z += e.z * rnew; pacc.w += e.w * rnew;
    };

    // block column-reduce + grid barrier + global reduce + c update
    // (identical structure/order to validated R2 kernel)
    auto col_reduce_barrier = [&](float4 pacc, int it) {
        float* Pcur = Pblk + (size_t)(it & 1) * NBLK * NE;
        plds[wib][lane] = pacc;
        __syncthreads();
        if (tid < NE) {
            const int hh = tid >> 2, kk = tid & 3;
            float t = 0.f;
#pragma unroll
            for (int w = 0; w < WPB; ++w)
#pragma unroll
                for (int gg = 0; gg < 4; ++gg)
                    t += ((const float*)&plds[w][gg * 16 + hh])[kk];
            __hip_atomic_store(&Pcur[blockIdx.x * NE + tid], t,
                               __ATOMIC_RELAXED, __HIP_MEMORY_SCOPE_AGENT);
        }
        __syncthreads();   // partials drained before arrival
        if (tid == 0) {
            __builtin_amdgcn_fence(__ATOMIC_RELEASE, "agent");
            __hip_atomic_fetch_add(&counters[it], 1u, __ATOMIC_RELAXED,
                                   __HIP_MEMORY_SCOPE_AGENT);
            while (__hip_atomic_load(&counters[it], __ATOMIC_RELAXED,
                                     __HIP_MEMORY_SCOPE_AGENT) < (unsigned)NBLK)
                __builtin_amdgcn_s_sleep(2);
            __builtin_amdgcn_fence(__ATOMIC_ACQUIRE, "agent");
        }
        __syncthreads();
        {
            const int col = tid & 63;
            const int chunk = tid >> 6;          // 16 chunks of 16 blocks
            const int b0 = chunk * (NBLK / 16);
            float t = 0.f;
#pragma unroll
            for (int b2 = 0; b2 < NBLK / 16; ++b2)
                t += __hip_atomic_load(&Pcur[(b0 + b2) * NE + col],
                                       __ATOMIC_RELAXED,
                                       __HIP_MEMORY_SCOPE_AGENT);
            s_red[chunk][col] = t;
        }
        __syncthreads();
        if (tid < NE) {
            float P = 0.f;
#pragma unroll
            for (int k = 0; k < 16; ++k) P += s_red[k][tid];
            float cj = ((float*)c_lds4)[tid];
            ((float*)c_lds4)[tid] = cj * col_target / (cj * P + EPS);
        }
        __syncthreads();
    };

    // 16 NAMED register-resident quads -- no array, no alloca possible.
    float4 R0, R1, R2, R3, R4, R5, R6, R7;
    float4 R8, R9, R10, R11, R12, R13, R14, R15;

#define LDSQ(j) ldsq[(wib * NL + (j)) * 64 + lane]

    // ---- pass 0: stream everything, stash exp into named regs / LDS -------
    // 4-deep rotating named buffers; literal indices throughout.
    {
        const float4 c4 = c_lds4[h];   // all ones
        float4 b0 = lp[0 * 64], b1 = lp[1 * 64], b2 = lp[2 * 64],
               b3 = lp[3 * 64];
        float4 pacc = {0.f, 0.f, 0.f, 0.f};

#define STEP0(q, BUF, STASH)                                     \
    {                                                            \
        float4 x_ = BUF;                                         \
        if ((q) + 4 < QPW) BUF = lp[(size_t)((q) + 4) * 64];     \
        float4 e_ = exp4(x_);                                    \
        STASH;                                                   \
        procq(e_, (q), c4, pacc, true);                          \
    }

        STEP0(0,  b0, R0 = e_)  STEP0(1,  b1, R1 = e_)
        STEP0(2,  b2, R2 = e_)  STEP0(3,  b3, R3 = e_)
        STEP0(4,  b0, R4 = e_)  STEP0(5,  b1, R5 = e_)
        STEP0(6,  b2, R6 = e_)  STEP0(7,  b3, R7 = e_)
        STEP0(8,  b0, R8 = e_)  STEP0(9,  b1, R9 = e_)
        STEP0(10, b2, R10 = e_) STEP0(11, b3, R11 = e_)
        STEP0(12, b0, R12 = e_) STEP0(13, b1, R13 = e_)
        STEP0(14, b2, R14 = e_) STEP0(15, b3, R15 = e_)
        STEP0(16, b0, LDSQ(0) = e_) STEP0(17, b1, LDSQ(1) = e_)
        STEP0(18, b2, LDSQ(2) = e_) STEP0(19, b3, LDSQ(3) = e_)
        STEP0(20, b0, LDSQ(4) = e_) STEP0(21, b1, LDSQ(5) = e_)
        STEP0(22, b2, LDSQ(6) = e_) STEP0(23, b3, LDSQ(7) = e_)
        STEP0(24, b0, (void)0) STEP0(25, b1, (void)0)
        STEP0(26, b2, (void)0) STEP0(27, b3, (void)0)
        STEP0(28, b0, (void)0) STEP0(29, b1, (void)0)
        STEP0(30, b2, (void)0) STEP0(31, b3, (void)0)
#undef STEP0

        col_reduce_barrier(pacc, 0);
    }

    // ---- passes 1..9: residents + small L2-resident streamed tail ---------
    for (int it = 1; it < ITERS; ++it) {
        const float4 c4 = c_lds4[h];
        float4 s0 = lp[24 * 64], s1 = lp[25 * 64], s2 = lp[26 * 64],
               s3 = lp[27 * 64];

        float4 pacc = {0.f, 0.f, 0.f, 0.f};
        procq(R0, 0, c4, pacc, false);   procq(R1, 1, c4, pacc, false);
        procq(R2, 2, c4, pacc, false);   procq(R3, 3, c4, pacc, false);
        procq(R4, 4, c4, pacc, false);   procq(R5, 5, c4, pacc, false);
        procq(R6, 6, c4, pacc, false);   procq(R7, 7, c4, pacc, false);
        procq(R8, 8, c4, pacc, false);   procq(R9, 9, c4, pacc, false);
        procq(R10, 10, c4, pacc, false); procq(R11, 11, c4, pacc, false);
        procq(R12, 12, c4, pacc, false); procq(R13, 13, c4, pacc, false);
        procq(R14, 14, c4, pacc, false); procq(R15, 15, c4, pacc, false);

        // LDS residents, 1-deep pipelined, literal indices
        {
            float4 l_ = LDSQ(0);
#define LSTEP(j)                                           \
    {                                                      \
        float4 ln_ = l_;                                   \
        if ((j) + 1 < NL) ln_ = LDSQ((j) + 1);             \
        procq(l_, NR + (j), c4, pacc, false);              \
        l_ = ln_;                                          \
    }
            LSTEP(0) LSTEP(1) LSTEP(2) LSTEP(3)
            LSTEP(4) LSTEP(5) LSTEP(6) LSTEP(7)
#undef LSTEP
        }

        // q24-27: rotate named bufs -> q28-31 loads issued before use
        {
            float4 x_;
            x_ = s0; s0 = lp[28 * 64]; procq(exp4(x_), 24, c4, pacc, false);
            x_ = s1; s1 = lp[29 * 64]; procq(exp4(x_), 25, c4, pacc, false);
            x_ = s2; s2 = lp[30 * 64]; procq(exp4(x_), 26, c4, pacc, false);
            x_ = s3; s3 = lp[31 * 64]; procq(exp4(x_), 27, c4, pacc, false);
            procq(exp4(s0), 28, c4, pacc, false);
            procq(exp4(s1), 29, c4, pacc, false);
            procq(exp4(s2), 30, c4, pacc, false);
            procq(exp4(s3), 31, c4, pacc, false);
        }

        col_reduce_barrier(pacc, it);
    }

    // ---- final: row-normalize + top-2 (DPP argmax) + renorm ---------------
    {
        const float4 c4 = c_lds4[h];
        const int base_col = h * 4;

        auto top2 = [&](float4 e, int q) {
            float4 u;
            u.x = e.x * c4.x; u.y = e.y * c4.y;
            u.z = e.z * c4.z; u.w = e.w * c4.w;
            float s = group16_sum(u.x + u.y + u.z + u.w);
            const int lrow = lrow0 + q * 4;
            float rold = r_lds[lrow];
            float rnew = rold / (rold * s + EPS);
            float4 val;
            val.x = u.x * rnew; val.y = u.y * rnew;
            val.z = u.z * rnew; val.w = u.w * rnew;

            float v = val.x; int i = base_col;
            if (val.y > v) { v = val.y; i = base_col + 1; }
            if (val.z > v) { v = val.z; i = base_col + 2; }
            if (val.w > v) { v = val.w; i = base_col + 3; }
            group16_argmax(v, i);
            float v1 = v; int i1 = i;

            float4 mv;
            mv.x = (i1 == base_col)     ? -INFINITY : val.x;
            mv.y = (i1 == base_col + 1) ? -INFINITY : val.y;
            mv.z = (i1 == base_col + 2) ? -INFINITY : val.z;
            mv.w = (i1 == base_col + 3) ? -INFINITY : val.w;
            v = mv.x; i = base_col;
            if (mv.y > v) { v = mv.y; i = base_col + 1; }
            if (mv.z > v) { v = mv.z; i = base_col + 2; }
            if (mv.w > v) { v = mv.w; i = base_col + 3; }
            group16_argmax(v, i);
            float v2 = v; int i2 = i;

            if (h == 0) {
                int row = (qbase + q) * 4 + g;
                float wsum = v1 + v2 + EPS;
                oidx[row] = make_float2((float)i1, (float)i2);
                ow[row] = make_float2(v1 / wsum, v2 / wsum);
            }
        };

        float4 s0 = lp[24 * 64], s1 = lp[25 * 64], s2 = lp[26 * 64],
               s3 = lp[27 * 64];

        top2(R0, 0);   top2(R1, 1);   top2(R2, 2);   top2(R3, 3);
        top2(R4, 4);   top2(R5, 5);   top2(R6, 6);   top2(R7, 7);
        top2(R8, 8);   top2(R9, 9);   top2(R10, 10); top2(R11, 11);
        top2(R12, 12); top2(R13, 13); top2(R14, 14); top2(R15, 15);

        {
            float4 l_ = LDSQ(0);
#define LSTEP2(j)                                          \
    {                                                      \
        float4 ln_ = l_;                                   \
        if ((j) + 1 < NL) ln_ = LDSQ((j) + 1);             \
        top2(l_, NR + (j));                                \
        l_ = ln_;                                          \
    }
            LSTEP2(0) LSTEP2(1) LSTEP2(2) LSTEP2(3)
            LSTEP2(4) LSTEP2(5) LSTEP2(6) LSTEP2(7)
#undef LSTEP2
        }

        {
            float4 x_;
            x_ = s0; s0 = lp[28 * 64]; top2(exp4(x_), 24);
            x_ = s1; s1 = lp[29 * 64]; top2(exp4(x_), 25);
            x_ = s2; s2 = lp[30 * 64]; top2(exp4(x_), 26);
            x_ = s3; s3 = lp[31 * 64]; top2(exp4(x_), 27);
            top2(exp4(s0), 28);
            top2(exp4(s1), 29);
            top2(exp4(s2), 30);
            top2(exp4(s3), 31);
        }
    }
#undef LDSQ
}

extern "C" void kernel_launch(void* const* d_in, const int* in_sizes, int n_in,
                              void* d_out, int out_size, void* d_ws, size_t ws_size,
                              hipStream_t stream) {
    const float* logits = (const float*)d_in[0];
    const int S = in_sizes[0] / NE;            // 524288
    const int nquads = S / 4;                  // 131072 (divisible by NWAVES)
    const float col_target = (float)S / (float)NE;

    float* Pblk = (float*)d_ws;                // 2*NBLK*64 floats (dbuf)
    unsigned* counters = (unsigned*)(Pblk + 2 * NBLK * NE);  // ITERS slots

    float* out = (float*)d_out;
    float2* oidx = (float2*)out;               // 2*S floats (indices)
    float2* ow = (float2*)(out + (size_t)2 * S);  // 2*S floats (weights)

    const size_t dyn_lds = (size_t)WPB * NL * 64 * sizeof(float4);  // 128 KB
    static bool attr_done = false;
    if (!attr_done) {
        hipFuncSetAttribute(reinterpret_cast<const void*>(sink_fused),
                            hipFuncAttributeMaxDynamicSharedMemorySize,
                            (int)dyn_lds);
        attr_done = true;
    }

    hipMemsetAsync(counters, 0, ITERS * sizeof(unsigned), stream);
    sink_fused<<<NBLK, TPB, dyn_lds, stream>>>((const float4*)logits, Pblk,
                                               counters, oidx, ow, nquads,
                                               col_target);
}

// Round 9
// 659.971 us; speedup vs baseline: 1.0755x; 1.0105x over previous
//
#include <hip/hip_runtime.h>
#include <math.h>

#define EPS 1e-6f
#define NE 64
#define TPB 1024
#define WPB 16             // waves per block
#define NBLK 256           // 1 block/CU (persistent residency requires this)
#define NWAVES (NBLK * WPB)   // 4096
#define ITERS 10
#define QPW 32             // quads per wave (131072 / 4096)
#define NR 16              // register-resident quads (named vars)
#define NL 8               // LDS-resident quads (128 KB dynamic)

// ---- DPP helpers: 16-lane-group reductions, pure VALU (no ds ops) ----
template <int ctrl>
__device__ __forceinline__ float dppf(float x) {
    return __int_as_float(__builtin_amdgcn_update_dpp(
        0, __float_as_int(x), ctrl, 0xf, 0xf, true));
}
template <int ctrl>
__device__ __forceinline__ int dppi(int x) {
    return __builtin_amdgcn_update_dpp(0, x, ctrl, 0xf, 0xf, true);
}

__device__ __forceinline__ float group16_sum(float v) {
    v += dppf<0xB1>(v);   // quad_perm xor 1
    v += dppf<0x4E>(v);   // quad_perm xor 2
    v += dppf<0x141>(v);  // row_half_mirror (xor 4)
    v += dppf<0x140>(v);  // row_mirror (xor 8)
    return v;
}

#define ARGMAX_STEP(CTRL)                                      \
    {                                                          \
        float ov = dppf<CTRL>(v);                              \
        int oi = dppi<CTRL>(i);                                \
        if (ov > v || (ov == v && oi < i)) { v = ov; i = oi; } \
    }

__device__ __forceinline__ void group16_argmax(float& v, int& i) {
    ARGMAX_STEP(0xB1)
    ARGMAX_STEP(0x4E)
    ARGMAX_STEP(0x141)
    ARGMAX_STEP(0x140)
}

__device__ __forceinline__ float4 exp4f(float4 v) {
    float4 e;
    e.x = __expf(v.x); e.y = __expf(v.y);
    e.z = __expf(v.z); e.w = __expf(v.w);
    return e;
}

// Persistent fused kernel, round 9: ALL hot-path closures -> macros.
// R5-R8 post-mortem: VGPR pinned at exactly 64 + ~112MB scratch writes
// across array/named-var/occupancy-attr variants. Diagnosis: the lambdas
// (procq / col_reduce_barrier) introduced in R5 are NOT being inlined;
// each call forces an ABI save/restore of all live residents (R0..R15 =
// 64 VGPRs) to scratch. R2-R4 (straight-line code) never showed this.
// Fix: textual inlining via macros -- no call can exist. Arithmetic
// forms/orders identical to validated R2 -> bitwise-identical output.
// Residency plan per wave (32 quads):
//   q 0..15  -> named VGPR vars (exp computed once in pass 0)
//   q 16..23 -> LDS (128 KB dynamic/block, exp computed once)
//   q 24..31 -> streamed each pass (4 MB/XCD aggregate = L2-resident)

// per-quad Sinkhorn row step (uses enclosing c4, pacc, h, lrow0, r_lds)
#define PROCQ(E, Q, FIRST)                                           \
    {                                                                \
        float4 e9 = (E);                                             \
        float s9 = e9.x * c4.x + e9.y * c4.y + e9.z * c4.z +         \
                   e9.w * c4.w;                                      \
        s9 = group16_sum(s9);                                        \
        const int lr9 = lrow0 + (Q) * 4;                             \
        float ro9 = (FIRST) ? 1.0f : r_lds[lr9];                     \
        float rn9 = ro9 / (ro9 * s9 + EPS);                          \
        if (h == 0) r_lds[lr9] = rn9;                                \
        pacc.x += e9.x * rn9; pacc.y += e9.y * rn9;                  \
        pacc.z += e9.z * rn9; pacc.w += e9.w * rn9;                  \
    }

// block column-reduce + grid barrier + global reduce + c update
// (identical structure/order to validated R2 kernel)
#define CRB(IT)                                                              \
    {                                                                        \
        float* Pcur = Pblk + (size_t)((IT) & 1) * NBLK * NE;                 \
        plds[wib][lane] = pacc;                                              \
        __syncthreads();                                                     \
        if (tid < NE) {                                                      \
            const int hh = tid >> 2, kk = tid & 3;                           \
            float t = 0.f;                                                   \
            _Pragma("unroll") for (int w = 0; w < WPB; ++w)                  \
                _Pragma("unroll") for (int gg = 0; gg < 4; ++gg)             \
                    t += ((const float*)&plds[w][gg * 16 + hh])[kk];         \
            __hip_atomic_store(&Pcur[blockIdx.x * NE + tid], t,              \
                               __ATOMIC_RELAXED, __HIP_MEMORY_SCOPE_AGENT);  \
        }                                                                    \
        __syncthreads();                                                     \
        if (tid == 0) {                                                      \
            __builtin_amdgcn_fence(__ATOMIC_RELEASE, "agent");               \
            __hip_atomic_fetch_add(&counters[(IT)], 1u, __ATOMIC_RELAXED,    \
                                   __HIP_MEMORY_SCOPE_AGENT);                \
            while (__hip_atomic_load(&counters[(IT)], __ATOMIC_RELAXED,      \
                                     __HIP_MEMORY_SCOPE_AGENT) <             \
                   (unsigned)NBLK)                                           \
                __builtin_amdgcn_s_sleep(2);                                 \
            __builtin_amdgcn_fence(__ATOMIC_ACQUIRE, "agent");               \
        }                                                                    \
        __syncthreads();                                                     \
        {                                                                    \
            const int col9 = tid & 63;                                       \
            const int chk9 = tid >> 6;                                       \
            const int cb9 = chk9 * (NBLK / 16);                              \
            float t = 0.f;                                                   \
            _Pragma("unroll") for (int b2 = 0; b2 < NBLK / 16; ++b2)         \
                t += __hip_atomic_load(&Pcur[(cb9 + b2) * NE + col9],        \
                                       __ATOMIC_RELAXED,                     \
                                       __HIP_MEMORY_SCOPE_AGENT);            \
            s_red[chk9][col9] = t;                                           \
        }                                                                    \
        __syncthreads();                                                     \
        if (tid < NE) {                                                      \
            float P = 0.f;                                                   \
            _Pragma("unroll") for (int k = 0; k < 16; ++k)                   \
                P += s_red[k][tid];                                          \
            float cj = ((float*)c_lds4)[tid];                                \
            ((float*)c_lds4)[tid] = cj * col_target / (cj * P + EPS);        \
        }                                                                    \
        __syncthreads();                                                     \
    }

// final-phase per-quad: row-normalize + top-2 + write (uses c4, base_col)
#define TOP2(E, Q)                                                   \
    {                                                                \
        float4 e8 = (E);                                             \
        float4 u8;                                                   \
        u8.x = e8.x * c4.x; u8.y = e8.y * c4.y;                      \
        u8.z = e8.z * c4.z; u8.w = e8.w * c4.w;                      \
        float s8 = group16_sum(u8.x + u8.y + u8.z + u8.w);           \
        const int lr8 = lrow0 + (Q) * 4;                             \
        float ro8 = r_lds[lr8];                                      \
        float rn8 = ro8 / (ro8 * s8 + EPS);                          \
        float4 val;                                                  \
        val.x = u8.x * rn8; val.y = u8.y * rn8;                      \
        val.z = u8.z * rn8; val.w = u8.w * rn8;                      \
        float v = val.x; int i = base_col;                           \
        if (val.y > v) { v = val.y; i = base_col + 1; }              \
        if (val.z > v) { v = val.z; i = base_col + 2; }              \
        if (val.w > v) { v = val.w; i = base_col + 3; }              \
        group16_argmax(v, i);                                        \
        float v1 = v; int i1 = i;                                    \
        float4 mv;                                                   \
        mv.x = (i1 == base_col)     ? -INFINITY : val.x;             \
        mv.y = (i1 == base_col + 1) ? -INFINITY : val.y;             \
        mv.z = (i1 == base_col + 2) ? -INFINITY : val.z;             \
        mv.w = (i1 == base_col + 3) ? -INFINITY : val.w;             \
        v = mv.x; i = base_col;                                      \
        if (mv.y > v) { v = mv.y; i = base_col + 1; }                \
        if (mv.z > v) { v = mv.z; i = base_col + 2; }                \
        if (mv.w > v) { v = mv.w; i = base_col + 3; }                \
        group16_argmax(v, i);                                        \
        float v2 = v; int i2 = i;                                    \
        if (h == 0) {                                                \
            int row = (qbase + (Q)) * 4 + g;                         \
            float wsum = v1 + v2 + EPS;                              \
            oidx[row] = make_float2((float)i1, (float)i2);           \
            ow[row] = make_float2(v1 / wsum, v2 / wsum);             \
        }                                                            \
    }

__global__ __launch_bounds__(TPB, 4) void sink_fused(
    const float4* __restrict__ logits4,
    float* __restrict__ Pblk,          // [2][NBLK][NE]
    unsigned* __restrict__ counters,   // [ITERS]
    float2* __restrict__ oidx, float2* __restrict__ ow,
    int nquads, float col_target) {
    extern __shared__ float4 ldsq[];   // [WPB*NL*64] = 128 KB resident data
    __shared__ float4 plds[WPB][64];   // 16 KB  block column-partial buffer
    __shared__ float s_red[16][NE];    // 4 KB   chunk-reduce buffer
    __shared__ float r_lds[WPB * 128]; // 8 KB   per-row r (2048 rows/block)
    __shared__ float4 c_lds4[NE / 4];  // 256 B  current column scaling

    const int tid = threadIdx.x;
    const int lane = tid & 63;
    const int wib = tid >> 6;
    const int g = lane >> 4;   // row within quad
    const int h = lane & 15;   // float4 slot within row
    const int qbase = (blockIdx.x * WPB + wib) * QPW;
    const float4* lp = logits4 + (size_t)qbase * 64 + lane;
    const int lrow0 = wib * 128 + g;

    if (tid < NE / 4) c_lds4[tid] = make_float4(1.f, 1.f, 1.f, 1.f);
    __syncthreads();

    // 16 NAMED register-resident quads
    float4 R0, R1, R2, R3, R4, R5, R6, R7;
    float4 R8, R9, R10, R11, R12, R13, R14, R15;

#define LDSQ(j) ldsq[(wib * NL + (j)) * 64 + lane]

    // ---- pass 0: stream everything, stash exp into named regs / LDS -------
    {
        const float4 c4 = c_lds4[h];   // all ones
        float4 b0 = lp[0 * 64], b1 = lp[1 * 64], b2 = lp[2 * 64],
               b3 = lp[3 * 64];
        float4 pacc = {0.f, 0.f, 0.f, 0.f};

#define STEP0(q, BUF, STASH)                                     \
    {                                                            \
        float4 x_ = BUF;                                         \
        if ((q) + 4 < QPW) BUF = lp[(size_t)((q) + 4) * 64];     \
        float4 e_ = exp4f(x_);                                   \
        STASH;                                                   \
        PROCQ(e_, (q), true)                                     \
    }

        STEP0(0,  b0, R0 = e_)  STEP0(1,  b1, R1 = e_)
        STEP0(2,  b2, R2 = e_)  STEP0(3,  b3, R3 = e_)
        STEP0(4,  b0, R4 = e_)  STEP0(5,  b1, R5 = e_)
        STEP0(6,  b2, R6 = e_)  STEP0(7,  b3, R7 = e_)
        STEP0(8,  b0, R8 = e_)  STEP0(9,  b1, R9 = e_)
        STEP0(10, b2, R10 = e_) STEP0(11, b3, R11 = e_)
        STEP0(12, b0, R12 = e_) STEP0(13, b1, R13 = e_)
        STEP0(14, b2, R14 = e_) STEP0(15, b3, R15 = e_)
        STEP0(16, b0, LDSQ(0) = e_) STEP0(17, b1, LDSQ(1) = e_)
        STEP0(18, b2, LDSQ(2) = e_) STEP0(19, b3, LDSQ(3) = e_)
        STEP0(20, b0, LDSQ(4) = e_) STEP0(21, b1, LDSQ(5) = e_)
        STEP0(22, b2, LDSQ(6) = e_) STEP0(23, b3, LDSQ(7) = e_)
        STEP0(24, b0, (void)0) STEP0(25, b1, (void)0)
        STEP0(26, b2, (void)0) STEP0(27, b3, (void)0)
        STEP0(28, b0, (void)0) STEP0(29, b1, (void)0)
        STEP0(30, b2, (void)0) STEP0(31, b3, (void)0)
#undef STEP0

        CRB(0)
    }

    // ---- passes 1..9: residents + small L2-resident streamed tail ---------
    for (int it = 1; it < ITERS; ++it) {
        const float4 c4 = c_lds4[h];
        float4 s0 = lp[24 * 64], s1 = lp[25 * 64], s2 = lp[26 * 64],
               s3 = lp[27 * 64];

        float4 pacc = {0.f, 0.f, 0.f, 0.f};
        PROCQ(R0, 0, false)   PROCQ(R1, 1, false)
        PROCQ(R2, 2, false)   PROCQ(R3, 3, false)
        PROCQ(R4, 4, false)   PROCQ(R5, 5, false)
        PROCQ(R6, 6, false)   PROCQ(R7, 7, false)
        PROCQ(R8, 8, false)   PROCQ(R9, 9, false)
        PROCQ(R10, 10, false) PROCQ(R11, 11, false)
        PROCQ(R12, 12, false) PROCQ(R13, 13, false)
        PROCQ(R14, 14, false) PROCQ(R15, 15, false)

        // LDS residents, 1-deep pipelined, literal indices
        {
            float4 l_ = LDSQ(0);
#define LSTEP(j)                                           \
    {                                                      \
        float4 ln_ = l_;                                   \
        if ((j) + 1 < NL) ln_ = LDSQ((j) + 1);             \
        PROCQ(l_, NR + (j), false)                         \
        l_ = ln_;                                          \
    }
            LSTEP(0) LSTEP(1) LSTEP(2) LSTEP(3)
            LSTEP(4) LSTEP(5) LSTEP(6) LSTEP(7)
#undef LSTEP
        }

        // q24-27: rotate named bufs -> q28-31 loads issued before use
        {
            float4 x_;
            x_ = s0; s0 = lp[28 * 64]; PROCQ(exp4f(x_), 24, false)
            x_ = s1; s1 = lp[29 * 64]; PROCQ(exp4f(x_), 25, false)
            x_ = s2; s2 = lp[30 * 64]; PROCQ(exp4f(x_), 26, false)
            x_ = s3; s3 = lp[31 * 64]; PROCQ(exp4f(x_), 27, false)
            PROCQ(exp4f(s0), 28, false)
            PROCQ(exp4f(s1), 29, false)
            PROCQ(exp4f(s2), 30, false)
            PROCQ(exp4f(s3), 31, false)
        }

        CRB(it)
    }

    // ---- final: row-normalize + top-2 (DPP argmax) + renorm ---------------
    {
        const float4 c4 = c_lds4[h];
        const int base_col = h * 4;

        float4 s0 = lp[24 * 64], s1 = lp[25 * 64], s2 = lp[26 * 64],
               s3 = lp[27 * 64];

        TOP2(R0, 0)   TOP2(R1, 1)   TOP2(R2, 2)   TOP2(R3, 3)
        TOP2(R4, 4)   TOP2(R5, 5)   TOP2(R6, 6)   TOP2(R7, 7)
        TOP2(R8, 8)   TOP2(R9, 9)   TOP2(R10, 10) TOP2(R11, 11)
        TOP2(R12, 12) TOP2(R13, 13) TOP2(R14, 14) TOP2(R15, 15)

        {
            float4 l_ = LDSQ(0);
#define LSTEP2(j)                                          \
    {                                                      \
        float4 ln_ = l_;                                   \
        if ((j) + 1 < NL) ln_ = LDSQ((j) + 1);             \
        TOP2(l_, NR + (j))                                 \
        l_ = ln_;                                          \
    }
            LSTEP2(0) LSTEP2(1) LSTEP2(2) LSTEP2(3)
            LSTEP2(4) LSTEP2(5) LSTEP2(6) LSTEP2(7)
#undef LSTEP2
        }

        {
            float4 x_;
            x_ = s0; s0 = lp[28 * 64]; TOP2(exp4f(x_), 24)
            x_ = s1; s1 = lp[29 * 64]; TOP2(exp4f(x_), 25)
            x_ = s2; s2 = lp[30 * 64]; TOP2(exp4f(x_), 26)
            x_ = s3; s3 = lp[31 * 64]; TOP2(exp4f(x_), 27)
            TOP2(exp4f(s0), 28)
            TOP2(exp4f(s1), 29)
            TOP2(exp4f(s2), 30)
            TOP2(exp4f(s3), 31)
        }
    }
#undef LDSQ
}

extern "C" void kernel_launch(void* const* d_in, const int* in_sizes, int n_in,
                              void* d_out, int out_size, void* d_ws, size_t ws_size,
                              hipStream_t stream) {
    const float* logits = (const float*)d_in[0];
    const int S = in_sizes[0] / NE;            // 524288
    const int nquads = S / 4;                  // 131072 (divisible by NWAVES)
    const float col_target = (float)S / (float)NE;

    float* Pblk = (float*)d_ws;                // 2*NBLK*64 floats (dbuf)
    unsigned* counters = (unsigned*)(Pblk + 2 * NBLK * NE);  // ITERS slots

    float* out = (float*)d_out;
    float2* oidx = (float2*)out;               // 2*S floats (indices)
    float2* ow = (float2*)(out + (size_t)2 * S);  // 2*S floats (weights)

    const size_t dyn_lds = (size_t)WPB * NL * 64 * sizeof(float4);  // 128 KB
    static bool attr_done = false;
    if (!attr_done) {
        hipFuncSetAttribute(reinterpret_cast<const void*>(sink_fused),
                            hipFuncAttributeMaxDynamicSharedMemorySize,
                            (int)dyn_lds);
        attr_done = true;
    }

    hipMemsetAsync(counters, 0, ITERS * sizeof(unsigned), stream);
    sink_fused<<<NBLK, TPB, dyn_lds, stream>>>((const float4*)logits, Pblk,
                                               counters, oidx, ow, nquads,
                                               col_target);
}